// Round 14
// baseline (150.604 us; speedup 1.0000x reference)
//
#include <hip/hip_runtime.h>
#include <hip/hip_bf16.h>
#include <math.h>

#define NS 4096      // samples
#define NC 512       // clusters
#define ND 64        // feature dim
#define NK 10        // classes
#define NPAIR 2080   // upper-triangle pairs (e<=d) of 64x64
#define KP 2176      // 2080 + 64 (linear) + 1 (const) + 31 zero-pad; 68*32
#define BOFF 2080
#define KOFF 2144
#define ZB 1024                     // d2-zeroing blocks
#define QB 2048                     // Q-precompute blocks (2 rows each)
// R14 gemm geometry: 64x64 tile, KSPLIT=4 (17 chunks each), grid 2048,
// LDS 32KB -> 5 blocks/CU
#define KSPLIT 4
#define KT_PER 17

typedef __attribute__((ext_vector_type(8))) short short8;
typedef __attribute__((ext_vector_type(4))) float floatx4;

__device__ inline unsigned short f2b(float x) {
    __hip_bfloat16 h = __float2bfloat16(x);           // RNE
    return __builtin_bit_cast(unsigned short, h);
}
__device__ inline float b2f(unsigned short u) {
    __hip_bfloat16 h = __builtin_bit_cast(__hip_bfloat16, u);
    return __bfloat162float(h);
}

// true v_readlane_b32 (lane is a compile-time literal at every use site)
__device__ inline float rlane(float v, int k) {
    return __builtin_bit_cast(float, __builtin_amdgcn_readlane(__builtin_bit_cast(int, v), k));
}

// async global->LDS, 16B per lane (m97 lever); dst = wave-uniform base + lane*16
__device__ inline void gl16(const void* g, void* l) {
    __builtin_amdgcn_global_load_lds(
        (const __attribute__((address_space(1))) unsigned int*)g,
        (__attribute__((address_space(3))) unsigned int*)l, 16, 0, 0);
}

// analytic (e,d) decode (bit-exact, HW-verified R6-R13: absmax 0.0 end-to-end)
__device__ inline uchar2 ed_decode(int p) {
    if (p < NPAIR) {
        const float s = sqrtf((float)(16641 - 8 * p));
        int e = (int)((129.0f - s) * 0.5f);
        int off = e * 64 - (e * (e - 1)) / 2;         // off(e)
        const int offn = off + (64 - e);              // off(e+1)
        if (p >= offn) { off = offn; ++e; }
        else if (p < off) { off -= (65 - e); --e; }
        return make_uchar2((unsigned char)e, (unsigned char)(e + (p - off)));
    } else if (p < KOFF) return make_uchar2((unsigned char)(p - BOFF), 64);
    else if (p == KOFF)  return make_uchar2(64, 64);
    return make_uchar2(65, 65);                       // zero pad
}

// ---------------- prep: 3 roles (R25 body, unchanged) -----------------------
__global__ __launch_bounds__(256, 4) void prep_kernel(
    const float* __restrict__ data, const float* __restrict__ S,
    const float* __restrict__ n, const float* __restrict__ mu,
    const int* __restrict__ clab,
    unsigned short* __restrict__ Qh, unsigned short* __restrict__ Ql,
    unsigned short* __restrict__ Bph, unsigned short* __restrict__ Bpl,
    float* __restrict__ d2, float* __restrict__ labf)
{
    __shared__ float AcolS[ND * (ND + 1)];            // Sinv mirror [64][65]
    __shared__ float cbuf[ND];                        // bvec staging
    __shared__ float rowbuf[2][ND];                   // GJ pivot-row broadcast
    __shared__ float kksS[1];
    __shared__ float zq[2][66];                       // Q-role rows + sentinels

    if (blockIdx.x >= NC + ZB) {                      // ---- role C: Q build --
        const int qb = blockIdx.x - (NC + ZB);        // 0..QB-1
        const int half = threadIdx.x >> 7;            // 2 rows per block
        const int i = threadIdx.x & 127;              // 2 waves per row
        const int row = qb * 2 + half;
        if (i < 64) zq[half][i] = data[(size_t)row * ND + i];
        else if (i == 64) { zq[half][64] = 1.0f; zq[half][65] = 0.0f; }
        __syncthreads();
        const float* __restrict__ zr = zq[half];
        unsigned short* __restrict__ qh = Qh + (size_t)row * KP;
        unsigned short* __restrict__ ql = Ql + (size_t)row * KP;
        #pragma unroll
        for (int t = 0; t < 4; ++t) {
            const int p0 = t * 512 + i * 4;
            uchar2 ed = ed_decode(p0);
            unsigned short h4[4], l4[4];
            #pragma unroll
            for (int r = 0; r < 4; ++r) {
                const float v = zr[ed.x] * zr[ed.y];
                h4[r] = f2b(v);
                l4[r] = f2b(v - b2f(h4[r]));
                ed = (ed.y < 63) ? make_uchar2(ed.x, (unsigned char)(ed.y + 1))
                                 : make_uchar2((unsigned char)(ed.x + 1),
                                               (unsigned char)(ed.x + 1));
            }
            *(short4*)&qh[p0] = make_short4((short)h4[0], (short)h4[1],
                                            (short)h4[2], (short)h4[3]);
            *(short4*)&ql[p0] = make_short4((short)l4[0], (short)l4[1],
                                            (short)l4[2], (short)l4[3]);
        }
        {                                             // tail: p = 2048 + i
            const int p = 2048 + i;
            const uchar2 ed = ed_decode(p);
            const float v = zr[ed.x] * zr[ed.y];
            const unsigned short h = f2b(v);
            const unsigned short l = f2b(v - b2f(h));
            qh[p] = h;
            ql[p] = l;
        }
        return;
    }

    if (blockIdx.x >= NC) {                           // ---- role B: d2 zero --
        const size_t base = (size_t)(blockIdx.x - NC) * 2048 + threadIdx.x * 8;
        *(float4*)&d2[base]     = make_float4(0.f, 0.f, 0.f, 0.f);
        *(float4*)&d2[base + 4] = make_float4(0.f, 0.f, 0.f, 0.f);
        return;
    }

    // ---- role A: 4-wave cooperative Gauss-Jordan ----
    const int c = blockIdx.x;
    const int tid = threadIdx.x;
    const int j = tid & 63;                           // column owned by lane
    const int w = tid >> 6;                           // wave -> rows 16w..16w+15
    const int rbase = w * 16;

    const float inv_nc = 1.0f / n[c];
    const float* __restrict__ Sc = S + (size_t)c * ND * ND + j;

    float4 B0, B1, B2, B3;
    // (1) pure loads -- 16 independent, all issued before any VALU below
#define LOADT(u) \
    const float t##u##0 = Sc[(rbase + 4*(u) + 0) * ND]; \
    const float t##u##1 = Sc[(rbase + 4*(u) + 1) * ND]; \
    const float t##u##2 = Sc[(rbase + 4*(u) + 2) * ND]; \
    const float t##u##3 = Sc[(rbase + 4*(u) + 3) * ND];
    LOADT(0) LOADT(1) LOADT(2) LOADT(3)
#undef LOADT
    __builtin_amdgcn_sched_barrier(0);                // loads stay batched
    // (2) scale + epsilon (same per-element op order as before)
#define SCALE(u) { \
    const float x0 = t##u##0 * inv_nc; \
    const float x1 = t##u##1 * inv_nc; \
    const float x2 = t##u##2 * inv_nc; \
    const float x3 = t##u##3 * inv_nc; \
    B##u.x = (rbase + 4*(u) + 0 == j) ? x0 + 1e-6f : x0; \
    B##u.y = (rbase + 4*(u) + 1 == j) ? x1 + 1e-6f : x1; \
    B##u.z = (rbase + 4*(u) + 2 == j) ? x2 + 1e-6f : x2; \
    B##u.w = (rbase + 4*(u) + 3 == j) ? x3 + 1e-6f : x3; }
    SCALE(0) SCALE(1) SCALE(2) SCALE(3)
#undef SCALE

#define UPD4(u, K) {                                                  \
    const float c0 = rlane(B##u.x, K);                                \
    const float c1 = rlane(B##u.y, K);                                \
    const float c2 = rlane(B##u.z, K);                                \
    const float c3 = rlane(B##u.w, K);                                \
    B##u.x = (om && (4*(u)+0 == ((K)&15))) ? rowk : B##u.x * am - c0 * rowk; \
    B##u.y = (om && (4*(u)+1 == ((K)&15))) ? rowk : B##u.y * am - c1 * rowk; \
    B##u.z = (om && (4*(u)+2 == ((K)&15))) ? rowk : B##u.z * am - c2 * rowk; \
    B##u.w = (om && (4*(u)+3 == ((K)&15))) ? rowk : B##u.w * am - c3 * rowk; \
}
#define STEPC(TL, C, K) {                                             \
    if (w == ((K) >> 4)) {                                            \
        const float rp = B##TL.C;         /* M[k][j]: own register */ \
        const float pv = rlane(rp, K);    /* pivot M[k][k] */         \
        const float ip = 1.0f / pv;                                   \
        rowbuf[(K) & 1][j] = (j == (K)) ? ip : rp * ip;               \
    }                                                                 \
    __syncthreads();                                                  \
    const float rowk = rowbuf[(K) & 1][j];                            \
    const float am = (j == (K)) ? 0.0f : 1.0f;                        \
    const bool om = (w == ((K) >> 4));                                \
    UPD4(0, K) UPD4(1, K) UPD4(2, K) UPD4(3, K)                       \
}
#define STEP4(T, TL) STEPC(TL, x, 4*(T)+0) STEPC(TL, y, 4*(T)+1) \
                     STEPC(TL, z, 4*(T)+2) STEPC(TL, w, 4*(T)+3)
#define FOR16P(M) M(0,0) M(1,1) M(2,2) M(3,3) M(4,0) M(5,1) M(6,2) M(7,3) \
                  M(8,0) M(9,1) M(10,2) M(11,3) M(12,0) M(13,1) M(14,2) M(15,3)
    FOR16P(STEP4)
#undef FOR16P
#undef STEP4
#undef STEPC
#undef UPD4

    // mirror Sinv into LDS for the pack gather (all 4 waves, disjoint rows)
#define MIR(u) *(float4*)&AcolS[j * (ND + 1) + rbase + 4*(u)] = B##u;
    MIR(0) MIR(1) MIR(2) MIR(3)
#undef MIR
    __syncthreads();                                  // AcolS complete

    if (w == 0) {                                     // y = Sinv*mu, kk, labels
        const float* __restrict__ muc = mu + (size_t)c * ND;
        float y = 0.f;
        #pragma unroll
        for (int t = 0; t < 16; ++t) {
            const float4 v = *(const float4*)&AcolS[j * (ND + 1) + 4 * t];
            y += v.x * muc[4*t]     + v.y * muc[4*t + 1]
               + v.z * muc[4*t + 2] + v.w * muc[4*t + 3];
        }
        cbuf[j] = -2.0f * y;                          // bvec values
        float kk = muc[j] * y;
        #pragma unroll
        for (int off = 32; off > 0; off >>= 1) kk += __shfl_down(kk, off);
        if (j == 0) {
            kksS[0] = kk;
            int lab = 0;
            for (int q = 0; q < NK; ++q) if (clab[c * NK + q] != 0) lab = q;
            labf[c] = (float)lab;
        }
    }
    __syncthreads();
    const float kks = kksS[0];

    unsigned short* __restrict__ ph = Bph + (size_t)c * KP;
    unsigned short* __restrict__ pl = Bpl + (size_t)c * KP;
    #pragma unroll
    for (int i = 0; i < 9; ++i) {                     // 34 iters split 4 ways
        const int t = w + 4 * i;
        if (t < KP / 64) {
            const int p = t * 64 + j;
            float val;
            if (p < NPAIR) {
                const uchar2 ed = ed_decode(p);
                val = (ed.x == ed.y) ? AcolS[ed.x * (ND + 1) + ed.x]
                    : (AcolS[ed.y * (ND + 1) + ed.x] + AcolS[ed.x * (ND + 1) + ed.y]);
            } else if (p < KOFF) val = cbuf[p - BOFF];
            else if (p == KOFF)  val = kks;
            else                 val = 0.f;
            const unsigned short h = f2b(val);
            const unsigned short l = f2b(val - b2f(h));
            ph[p] = h;
            pl[p] = l;
        }
    }
}

// ---------------- d2 = Q·Beta^T, 64x64 tile, 5 blocks/CU (R14) --------------
// R29: occupancy was the first gemm lever to move the needle (R13: 2->3
// blocks/CU, total -3.9us, gemm left top-5). Push it: 64x64 tile, LDS 32KB
// (4 bufs x 2dbuf x 4KB) -> 5 blocks/CU = 20 waves/CU (~62% occupancy);
// grid (64,8,4) = 2048 blocks = 8/CU queued -> block-level pipelining on top
// of wave overlap. 4 gl16/stage, counted vmcnt(4). Same swizzle algebra,
// same k-partition as R7-R12 (17 chunks/split), same staged bits and MFMA
// accumulation order per (m,n,kchunk) -> d2 bit-identical.
__global__ __launch_bounds__(256, 5) void gemm_kernel(
    const unsigned short* __restrict__ Qh, const unsigned short* __restrict__ Ql,
    const unsigned short* __restrict__ Bph, const unsigned short* __restrict__ Bpl,
    float* __restrict__ d2)
{
    __shared__ unsigned short AhS[2][64 * 32], AlS[2][64 * 32];   // 16KB
    __shared__ unsigned short BhS[2][64 * 32], BlS[2][64 * 32];   // 16KB

    const int tid  = threadIdx.x;
    const int lane = tid & 63, w = tid >> 6;
    const int quad = lane >> 4, rlo = lane & 15;

    const int m0 = blockIdx.x * 64;               // sample tile
    const int n0 = blockIdx.y * 64;               // cluster tile
    const int koff0 = blockIdx.z * KT_PER * 32;   // K-slice start

    // staging: thread -> row tid>>2, seg tid&3 (16B units); source seg
    // pre-swizzled so LDS[row][slot] = global seg slot^((row>>2)&3)
    const int srow = tid >> 2;
    const int sswz = (tid & 3) ^ ((srow >> 2) & 3);
    const unsigned short* aGh = Qh + (size_t)(m0 + srow) * KP + koff0 + sswz * 8;
    const unsigned short* aGl = Ql + (size_t)(m0 + srow) * KP + koff0 + sswz * 8;
    const unsigned short* bGh = Bph + (size_t)(n0 + srow) * KP + koff0 + sswz * 8;
    const unsigned short* bGl = Bpl + (size_t)(n0 + srow) * KP + koff0 + sswz * 8;
    const int swz8 = (quad ^ ((rlo >> 2) & 3)) * 8;   // read-side slot

    floatx4 acc[4] = {};

#define STAGE(b, t) {                                                 \
        const int _ko = (t) * 32;                                     \
        gl16(aGh + _ko, &AhS[b][tid * 8]);                            \
        gl16(aGl + _ko, &AlS[b][tid * 8]);                            \
        gl16(bGh + _ko, &BhS[b][tid * 8]);                            \
        gl16(bGl + _ko, &BlS[b][tid * 8]);                            \
    }

    // prologue: tiles 0 and 1 in flight (4 loads each); wait for tile 0
    STAGE(0, 0)
    STAGE(1, 1)
    asm volatile("s_waitcnt vmcnt(4)" ::: "memory");
    __builtin_amdgcn_s_barrier();
    __builtin_amdgcn_sched_barrier(0);

    for (int kt = 0; kt < KT_PER; ++kt) {
        const int cur = kt & 1;

        // compiler-visible ds_reads: scheduler interleaves with MFMAs below
        short8 ah[4], al[4], bh, bl;
        #pragma unroll
        for (int i = 0; i < 4; ++i) {
            ah[i] = *(const short8*)&AhS[cur][(i * 16 + rlo) * 32 + swz8];
            al[i] = *(const short8*)&AlS[cur][(i * 16 + rlo) * 32 + swz8];
        }
        {
            const int r = w * 16 + rlo;
            bh = *(const short8*)&BhS[cur][r * 32 + swz8];
            bl = *(const short8*)&BlS[cur][r * 32 + swz8];
        }

        __builtin_amdgcn_s_setprio(1);
        #pragma unroll
        for (int i = 0; i < 4; ++i) {
            acc[i] = __builtin_amdgcn_mfma_f32_16x16x32_bf16(al[i], bh, acc[i], 0, 0, 0);
            acc[i] = __builtin_amdgcn_mfma_f32_16x16x32_bf16(ah[i], bl, acc[i], 0, 0, 0);
            acc[i] = __builtin_amdgcn_mfma_f32_16x16x32_bf16(ah[i], bh, acc[i], 0, 0, 0);
        }
        __builtin_amdgcn_s_setprio(0);

        asm volatile("s_waitcnt lgkmcnt(0)" ::: "memory");
        __builtin_amdgcn_s_barrier();                 // all waves done w/ cur

        if (kt < KT_PER - 2) STAGE(cur, kt + 2)       // overwrite now safe

        if (kt < KT_PER - 2) {
            asm volatile("s_waitcnt vmcnt(4)" ::: "memory");   // kt+1 landed
        } else {
            asm volatile("s_waitcnt vmcnt(0)" ::: "memory");   // tail drain
        }
        __builtin_amdgcn_s_barrier();                 // buf[cur^1] published
        __builtin_amdgcn_sched_barrier(0);            // next reads stay below
    }
#undef STAGE

    // C layout (verified m89): col = lane&15, row = (lane>>4)*4 + reg
    #pragma unroll
    for (int i = 0; i < 4; ++i) {
        const int m = m0 + i * 16 + quad * 4;
        const int nn = n0 + w * 16 + rlo;
        #pragma unroll
        for (int r = 0; r < 4; ++r)
            atomicAdd(&d2[(size_t)(m + r) * NC + nn], acc[i][r]);
    }
}

// ---------------- scores / argmaxes: 4 waves/block, one sample per wave -----
__global__ __launch_bounds__(256) void score_kernel(
    const float* __restrict__ d2, const float* __restrict__ labf,
    float* __restrict__ out)
{
    const int s = blockIdx.x * 4 + (threadIdx.x >> 6);
    const int l = threadIdx.x & 63;

    float numer[NK];
    #pragma unroll
    for (int q = 0; q < NK; ++q) numer[q] = 0.f;
    float denom = 0.f, gmax = -1.f;
    int gidx = 0;

    #pragma unroll
    for (int i = 0; i < NC / 256; ++i) {         // float4 per lane, index-ascending
        const int c0 = i * 256 + l * 4;
        const float4 v = *(const float4*)&d2[(size_t)s * NC + c0];
        #pragma unroll
        for (int r = 0; r < 4; ++r) {
            const int c = c0 + r;
            const float G = __expf(-0.5f * ((const float*)&v)[r]);
            denom += G;
            const int lab = (int)labf[c];
            #pragma unroll
            for (int q = 0; q < NK; ++q) numer[q] += (q == lab) ? G : 0.f;
            if (G > gmax) { gmax = G; gidx = c; }   // strict > keeps first index
        }
    }

    #pragma unroll
    for (int off = 32; off > 0; off >>= 1) {
        const float og = __shfl_down(gmax, off);
        const int   oi = __shfl_down(gidx, off);
        if (og > gmax || (og == gmax && oi < gidx)) { gmax = og; gidx = oi; }
        denom += __shfl_down(denom, off);
        #pragma unroll
        for (int q = 0; q < NK; ++q) numer[q] += __shfl_down(numer[q], off);
    }

    if (l == 0) {
        const float inv = 1.0f / (denom + 1e-12f);
        float best = -1.f; int pk = 0;
        #pragma unroll
        for (int q = 0; q < NK; ++q) {
            const float sc = numer[q] * inv;
            out[(size_t)s * NK + q] = sc;
            if (sc > best) { best = sc; pk = q; }
        }
        out[(size_t)NS * NK + s]      = (float)pk;    // pred
        out[(size_t)NS * NK + NS + s] = (float)gidx;  // clusters
    }
}

extern "C" void kernel_launch(void* const* d_in, const int* in_sizes, int n_in,
                              void* d_out, int out_size, void* d_ws, size_t ws_size,
                              hipStream_t stream)
{
    const float* data = (const float*)d_in[0];
    const float* n    = (const float*)d_in[2];
    const float* mu   = (const float*)d_in[3];
    const float* S    = (const float*)d_in[4];
    const int*   clab = (const int*)d_in[5];

    char* w = (char*)d_ws;
    unsigned short* Qh  = (unsigned short*)(w);                 // 17,825,792 B
    unsigned short* Ql  = (unsigned short*)(w + 17825792);      // 17,825,792 B
    unsigned short* Bph = (unsigned short*)(w + 35651584);      //  2,228,224 B
    unsigned short* Bpl = (unsigned short*)(w + 37879808);      //  2,228,224 B
    float* d2   = (float*)(w + 40108032);                       //  8,388,608 B
    float* labf = (float*)(w + 48496640);                       //      2,048 B

    hipLaunchKernelGGL(prep_kernel,  dim3(NC + ZB + QB), dim3(256), 0, stream,
                       data, S, n, mu, clab, Qh, Ql, Bph, Bpl, d2, labf);
    hipLaunchKernelGGL(gemm_kernel,  dim3(NS / 64, NC / 64, KSPLIT), dim3(256), 0, stream,
                       Qh, Ql, Bph, Bpl, d2);
    hipLaunchKernelGGL(score_kernel, dim3(NS / 4), dim3(256), 0, stream,
                       d2, labf, (float*)d_out);
}

// Round 15
// 143.918 us; speedup vs baseline: 1.0465x; 1.0465x over previous
//
#include <hip/hip_runtime.h>
#include <hip/hip_bf16.h>
#include <math.h>

#define NS 4096      // samples
#define NC 512       // clusters
#define ND 64        // feature dim
#define NK 10        // classes
#define NPAIR 2080   // upper-triangle pairs (e<=d) of 64x64
#define KP 2176      // 2080 + 64 (linear) + 1 (const) + 31 zero-pad; 68*32
#define BOFF 2080
#define KOFF 2144
#define QB 2048                     // Q-precompute blocks (2 rows each)
#define KT 68                       // full-K chunks (no split)

typedef __attribute__((ext_vector_type(8))) short short8;
typedef __attribute__((ext_vector_type(4))) float floatx4;

__device__ inline unsigned short f2b(float x) {
    __hip_bfloat16 h = __float2bfloat16(x);           // RNE
    return __builtin_bit_cast(unsigned short, h);
}
__device__ inline float b2f(unsigned short u) {
    __hip_bfloat16 h = __builtin_bit_cast(__hip_bfloat16, u);
    return __bfloat162float(h);
}

// true v_readlane_b32 (lane is a compile-time literal at every use site)
__device__ inline float rlane(float v, int k) {
    return __builtin_bit_cast(float, __builtin_amdgcn_readlane(__builtin_bit_cast(int, v), k));
}

// async global->LDS, 16B per lane (m97 lever); dst = wave-uniform base + lane*16
__device__ inline void gl16(const void* g, void* l) {
    __builtin_amdgcn_global_load_lds(
        (const __attribute__((address_space(1))) unsigned int*)g,
        (__attribute__((address_space(3))) unsigned int*)l, 16, 0, 0);
}

// analytic (e,d) decode (bit-exact, HW-verified R6-R14: absmax 0.0 end-to-end)
__device__ inline uchar2 ed_decode(int p) {
    if (p < NPAIR) {
        const float s = sqrtf((float)(16641 - 8 * p));
        int e = (int)((129.0f - s) * 0.5f);
        int off = e * 64 - (e * (e - 1)) / 2;         // off(e)
        const int offn = off + (64 - e);              // off(e+1)
        if (p >= offn) { off = offn; ++e; }
        else if (p < off) { off -= (65 - e); --e; }
        return make_uchar2((unsigned char)e, (unsigned char)(e + (p - off)));
    } else if (p < KOFF) return make_uchar2((unsigned char)(p - BOFF), 64);
    else if (p == KOFF)  return make_uchar2(64, 64);
    return make_uchar2(65, 65);                       // zero pad
}

// ---------------- prep: 2 roles (role B d2-zeroing DELETED: no more split-K
// atomics -> gemm plain-stores d2, no zero init needed) ----------------------
//  role A (blk <  NC):   Sigma^-1 (4-wave coop GJ) + beta pack
//  role C (blk >= NC):   Q precompute, quad-walked
__global__ __launch_bounds__(256, 4) void prep_kernel(
    const float* __restrict__ data, const float* __restrict__ S,
    const float* __restrict__ n, const float* __restrict__ mu,
    const int* __restrict__ clab,
    unsigned short* __restrict__ Qh, unsigned short* __restrict__ Ql,
    unsigned short* __restrict__ Bph, unsigned short* __restrict__ Bpl,
    float* __restrict__ labf)
{
    __shared__ float AcolS[ND * (ND + 1)];            // Sinv mirror [64][65]
    __shared__ float cbuf[ND];                        // bvec staging
    __shared__ float rowbuf[2][ND];                   // GJ pivot-row broadcast
    __shared__ float kksS[1];
    __shared__ float zq[2][66];                       // Q-role rows + sentinels

    if (blockIdx.x >= NC) {                           // ---- role C: Q build --
        const int qb = blockIdx.x - NC;               // 0..QB-1
        const int half = threadIdx.x >> 7;            // 2 rows per block
        const int i = threadIdx.x & 127;              // 2 waves per row
        const int row = qb * 2 + half;
        if (i < 64) zq[half][i] = data[(size_t)row * ND + i];
        else if (i == 64) { zq[half][64] = 1.0f; zq[half][65] = 0.0f; }
        __syncthreads();
        const float* __restrict__ zr = zq[half];
        unsigned short* __restrict__ qh = Qh + (size_t)row * KP;
        unsigned short* __restrict__ ql = Ql + (size_t)row * KP;
        #pragma unroll
        for (int t = 0; t < 4; ++t) {
            const int p0 = t * 512 + i * 4;
            uchar2 ed = ed_decode(p0);
            unsigned short h4[4], l4[4];
            #pragma unroll
            for (int r = 0; r < 4; ++r) {
                const float v = zr[ed.x] * zr[ed.y];
                h4[r] = f2b(v);
                l4[r] = f2b(v - b2f(h4[r]));
                ed = (ed.y < 63) ? make_uchar2(ed.x, (unsigned char)(ed.y + 1))
                                 : make_uchar2((unsigned char)(ed.x + 1),
                                               (unsigned char)(ed.x + 1));
            }
            *(short4*)&qh[p0] = make_short4((short)h4[0], (short)h4[1],
                                            (short)h4[2], (short)h4[3]);
            *(short4*)&ql[p0] = make_short4((short)l4[0], (short)l4[1],
                                            (short)l4[2], (short)l4[3]);
        }
        {                                             // tail: p = 2048 + i
            const int p = 2048 + i;
            const uchar2 ed = ed_decode(p);
            const float v = zr[ed.x] * zr[ed.y];
            const unsigned short h = f2b(v);
            const unsigned short l = f2b(v - b2f(h));
            qh[p] = h;
            ql[p] = l;
        }
        return;
    }

    // ---- role A: 4-wave cooperative Gauss-Jordan ----
    const int c = blockIdx.x;
    const int tid = threadIdx.x;
    const int j = tid & 63;                           // column owned by lane
    const int w = tid >> 6;                           // wave -> rows 16w..16w+15
    const int rbase = w * 16;

    const float inv_nc = 1.0f / n[c];
    const float* __restrict__ Sc = S + (size_t)c * ND * ND + j;

    float4 B0, B1, B2, B3;
    // (1) pure loads -- 16 independent, all issued before any VALU below
#define LOADT(u) \
    const float t##u##0 = Sc[(rbase + 4*(u) + 0) * ND]; \
    const float t##u##1 = Sc[(rbase + 4*(u) + 1) * ND]; \
    const float t##u##2 = Sc[(rbase + 4*(u) + 2) * ND]; \
    const float t##u##3 = Sc[(rbase + 4*(u) + 3) * ND];
    LOADT(0) LOADT(1) LOADT(2) LOADT(3)
#undef LOADT
    __builtin_amdgcn_sched_barrier(0);                // loads stay batched
    // (2) scale + epsilon (same per-element op order as before)
#define SCALE(u) { \
    const float x0 = t##u##0 * inv_nc; \
    const float x1 = t##u##1 * inv_nc; \
    const float x2 = t##u##2 * inv_nc; \
    const float x3 = t##u##3 * inv_nc; \
    B##u.x = (rbase + 4*(u) + 0 == j) ? x0 + 1e-6f : x0; \
    B##u.y = (rbase + 4*(u) + 1 == j) ? x1 + 1e-6f : x1; \
    B##u.z = (rbase + 4*(u) + 2 == j) ? x2 + 1e-6f : x2; \
    B##u.w = (rbase + 4*(u) + 3 == j) ? x3 + 1e-6f : x3; }
    SCALE(0) SCALE(1) SCALE(2) SCALE(3)
#undef SCALE

#define UPD4(u, K) {                                                  \
    const float c0 = rlane(B##u.x, K);                                \
    const float c1 = rlane(B##u.y, K);                                \
    const float c2 = rlane(B##u.z, K);                                \
    const float c3 = rlane(B##u.w, K);                                \
    B##u.x = (om && (4*(u)+0 == ((K)&15))) ? rowk : B##u.x * am - c0 * rowk; \
    B##u.y = (om && (4*(u)+1 == ((K)&15))) ? rowk : B##u.y * am - c1 * rowk; \
    B##u.z = (om && (4*(u)+2 == ((K)&15))) ? rowk : B##u.z * am - c2 * rowk; \
    B##u.w = (om && (4*(u)+3 == ((K)&15))) ? rowk : B##u.w * am - c3 * rowk; \
}
#define STEPC(TL, C, K) {                                             \
    if (w == ((K) >> 4)) {                                            \
        const float rp = B##TL.C;         /* M[k][j]: own register */ \
        const float pv = rlane(rp, K);    /* pivot M[k][k] */         \
        const float ip = 1.0f / pv;                                   \
        rowbuf[(K) & 1][j] = (j == (K)) ? ip : rp * ip;               \
    }                                                                 \
    __syncthreads();                                                  \
    const float rowk = rowbuf[(K) & 1][j];                            \
    const float am = (j == (K)) ? 0.0f : 1.0f;                        \
    const bool om = (w == ((K) >> 4));                                \
    UPD4(0, K) UPD4(1, K) UPD4(2, K) UPD4(3, K)                       \
}
#define STEP4(T, TL) STEPC(TL, x, 4*(T)+0) STEPC(TL, y, 4*(T)+1) \
                     STEPC(TL, z, 4*(T)+2) STEPC(TL, w, 4*(T)+3)
#define FOR16P(M) M(0,0) M(1,1) M(2,2) M(3,3) M(4,0) M(5,1) M(6,2) M(7,3) \
                  M(8,0) M(9,1) M(10,2) M(11,3) M(12,0) M(13,1) M(14,2) M(15,3)
    FOR16P(STEP4)
#undef FOR16P
#undef STEP4
#undef STEPC
#undef UPD4

    // mirror Sinv into LDS for the pack gather (all 4 waves, disjoint rows)
#define MIR(u) *(float4*)&AcolS[j * (ND + 1) + rbase + 4*(u)] = B##u;
    MIR(0) MIR(1) MIR(2) MIR(3)
#undef MIR
    __syncthreads();                                  // AcolS complete

    if (w == 0) {                                     // y = Sinv*mu, kk, labels
        const float* __restrict__ muc = mu + (size_t)c * ND;
        float y = 0.f;
        #pragma unroll
        for (int t = 0; t < 16; ++t) {
            const float4 v = *(const float4*)&AcolS[j * (ND + 1) + 4 * t];
            y += v.x * muc[4*t]     + v.y * muc[4*t + 1]
               + v.z * muc[4*t + 2] + v.w * muc[4*t + 3];
        }
        cbuf[j] = -2.0f * y;                          // bvec values
        float kk = muc[j] * y;
        #pragma unroll
        for (int off = 32; off > 0; off >>= 1) kk += __shfl_down(kk, off);
        if (j == 0) {
            kksS[0] = kk;
            int lab = 0;
            for (int q = 0; q < NK; ++q) if (clab[c * NK + q] != 0) lab = q;
            labf[c] = (float)lab;
        }
    }
    __syncthreads();
    const float kks = kksS[0];

    unsigned short* __restrict__ ph = Bph + (size_t)c * KP;
    unsigned short* __restrict__ pl = Bpl + (size_t)c * KP;
    #pragma unroll
    for (int i = 0; i < 9; ++i) {                     // 34 iters split 4 ways
        const int t = w + 4 * i;
        if (t < KP / 64) {
            const int p = t * 64 + j;
            float val;
            if (p < NPAIR) {
                const uchar2 ed = ed_decode(p);
                val = (ed.x == ed.y) ? AcolS[ed.x * (ND + 1) + ed.x]
                    : (AcolS[ed.y * (ND + 1) + ed.x] + AcolS[ed.x * (ND + 1) + ed.y]);
            } else if (p < KOFF) val = cbuf[p - BOFF];
            else if (p == KOFF)  val = kks;
            else                 val = 0.f;
            const unsigned short h = f2b(val);
            const unsigned short l = f2b(val - b2f(h));
            ph[p] = h;
            pl[p] = l;
        }
    }
}

// ---------------- d2 = Q·Beta^T, 64x32 tile, FULL-K, ZERO ATOMICS (R15) -----
// R30: the cross-round ledger finally fingered the atomics. WRITE_SIZE =
// KSPLIT x |d2| every round (each split pass RMW-evicts d2); the ONLY gemm
// change that ever moved time was KSPLIT 4->3 (R13: atomics -25%, -4-6us);
// occupancy 2x (R14) was null. 8.4M device-scope atomicAdds at the L2
// coherence point ~ 27us of unhideable serialized work. Fix: KSPLIT=1 --
// each block owns its (m,n) tile over the FULL K in registers and plain-
// stores d2 once (no RMW, no zero-init, prep role B deleted). Tile 64x32,
// grid (64,16)=1024, LDS 24KB -> 4 resident/CU. Per phase/wave: 3 gl16,
// 6 ds_read_b128, 6 MFMA; counted vmcnt(3); same swizzle algebra and
// 3-MFMA hi/lo order per k-chunk (chunks now one in-order fp32 chain).
__global__ __launch_bounds__(256, 6) void gemm_kernel(
    const unsigned short* __restrict__ Qh, const unsigned short* __restrict__ Ql,
    const unsigned short* __restrict__ Bph, const unsigned short* __restrict__ Bpl,
    float* __restrict__ d2)
{
    __shared__ unsigned short AhS[2][64 * 32], AlS[2][64 * 32];   // 16KB
    __shared__ unsigned short BhS[2][32 * 32], BlS[2][32 * 32];   // 8KB

    const int tid  = threadIdx.x;
    const int lane = tid & 63, w = tid >> 6;
    const int quad = lane >> 4, rlo = lane & 15;

    const int m0 = blockIdx.x * 64;               // sample tile
    const int n0 = blockIdx.y * 32;               // cluster tile

    // A staging: thread -> row tid>>2, seg tid&3; source seg pre-swizzled so
    // LDS[row][slot] = global seg slot^((row>>2)&3); dst linear tid*16B.
    const int srow = tid >> 2;
    const int sswz = (tid & 3) ^ ((srow >> 2) & 3);
    const unsigned short* aGh = Qh + (size_t)(m0 + srow) * KP + sswz * 8;
    const unsigned short* aGl = Ql + (size_t)(m0 + srow) * KP + sswz * 8;
    // B staging: 32 rows x 4 segs = 128 chunks; waves 0-1 -> Bh, waves 2-3 -> Bl
    const int bt  = tid & 127;
    const int brow = bt >> 2;
    const int bswz = (bt & 3) ^ ((brow >> 2) & 3);
    const unsigned short* bG = (tid < 128 ? Bph : Bpl)
                             + (size_t)(n0 + brow) * KP + bswz * 8;
    const int swz8 = (quad ^ ((rlo >> 2) & 3)) * 8;   // read-side slot

    floatx4 acc[2] = {};

#define STAGE(b, t) {                                                 \
        const int _ko = (t) * 32;                                     \
        gl16(aGh + _ko, &AhS[b][tid * 8]);                            \
        gl16(aGl + _ko, &AlS[b][tid * 8]);                            \
        gl16(bG + _ko, (tid < 128) ? &BhS[b][bt * 8]                  \
                                   : &BlS[b][bt * 8]);                \
    }

    // prologue: tiles 0 and 1 in flight (3 gl16/wave each); wait for tile 0
    STAGE(0, 0)
    STAGE(1, 1)
    asm volatile("s_waitcnt vmcnt(3)" ::: "memory");
    __builtin_amdgcn_s_barrier();
    __builtin_amdgcn_sched_barrier(0);

    for (int kt = 0; kt < KT; ++kt) {
        const int cur = kt & 1;

        // compiler-visible ds_reads: scheduler interleaves with MFMAs below
        short8 ah, al, bh[2], bl[2];
        ah = *(const short8*)&AhS[cur][(w * 16 + rlo) * 32 + swz8];
        al = *(const short8*)&AlS[cur][(w * 16 + rlo) * 32 + swz8];
        #pragma unroll
        for (int j2 = 0; j2 < 2; ++j2) {
            bh[j2] = *(const short8*)&BhS[cur][(j2 * 16 + rlo) * 32 + swz8];
            bl[j2] = *(const short8*)&BlS[cur][(j2 * 16 + rlo) * 32 + swz8];
        }

        __builtin_amdgcn_s_setprio(1);
        #pragma unroll
        for (int j2 = 0; j2 < 2; ++j2) {
            acc[j2] = __builtin_amdgcn_mfma_f32_16x16x32_bf16(al, bh[j2], acc[j2], 0, 0, 0);
            acc[j2] = __builtin_amdgcn_mfma_f32_16x16x32_bf16(ah, bl[j2], acc[j2], 0, 0, 0);
            acc[j2] = __builtin_amdgcn_mfma_f32_16x16x32_bf16(ah, bh[j2], acc[j2], 0, 0, 0);
        }
        __builtin_amdgcn_s_setprio(0);

        asm volatile("s_waitcnt lgkmcnt(0)" ::: "memory");
        __builtin_amdgcn_s_barrier();                 // all waves done w/ cur

        if (kt < KT - 2) STAGE(cur, kt + 2)           // overwrite now safe

        if (kt < KT - 2) {
            asm volatile("s_waitcnt vmcnt(3)" ::: "memory");   // kt+1 landed
        } else {
            asm volatile("s_waitcnt vmcnt(0)" ::: "memory");   // tail drain
        }
        __builtin_amdgcn_s_barrier();                 // buf[cur^1] published
        __builtin_amdgcn_sched_barrier(0);            // next reads stay below
    }
#undef STAGE

    // C layout (verified m89): col = lane&15, row = (lane>>4)*4 + reg
    // plain stores -- sole writer of each element (no split-K)
    #pragma unroll
    for (int j2 = 0; j2 < 2; ++j2) {
        const int m = m0 + w * 16 + quad * 4;
        const int nn = n0 + j2 * 16 + rlo;
        #pragma unroll
        for (int r = 0; r < 4; ++r)
            d2[(size_t)(m + r) * NC + nn] = acc[j2][r];
    }
}

// ---------------- scores / argmaxes: 4 waves/block, one sample per wave -----
__global__ __launch_bounds__(256) void score_kernel(
    const float* __restrict__ d2, const float* __restrict__ labf,
    float* __restrict__ out)
{
    const int s = blockIdx.x * 4 + (threadIdx.x >> 6);
    const int l = threadIdx.x & 63;

    float numer[NK];
    #pragma unroll
    for (int q = 0; q < NK; ++q) numer[q] = 0.f;
    float denom = 0.f, gmax = -1.f;
    int gidx = 0;

    #pragma unroll
    for (int i = 0; i < NC / 256; ++i) {         // float4 per lane, index-ascending
        const int c0 = i * 256 + l * 4;
        const float4 v = *(const float4*)&d2[(size_t)s * NC + c0];
        #pragma unroll
        for (int r = 0; r < 4; ++r) {
            const int c = c0 + r;
            const float G = __expf(-0.5f * ((const float*)&v)[r]);
            denom += G;
            const int lab = (int)labf[c];
            #pragma unroll
            for (int q = 0; q < NK; ++q) numer[q] += (q == lab) ? G : 0.f;
            if (G > gmax) { gmax = G; gidx = c; }   // strict > keeps first index
        }
    }

    #pragma unroll
    for (int off = 32; off > 0; off >>= 1) {
        const float og = __shfl_down(gmax, off);
        const int   oi = __shfl_down(gidx, off);
        if (og > gmax || (og == gmax && oi < gidx)) { gmax = og; gidx = oi; }
        denom += __shfl_down(denom, off);
        #pragma unroll
        for (int q = 0; q < NK; ++q) numer[q] += __shfl_down(numer[q], off);
    }

    if (l == 0) {
        const float inv = 1.0f / (denom + 1e-12f);
        float best = -1.f; int pk = 0;
        #pragma unroll
        for (int q = 0; q < NK; ++q) {
            const float sc = numer[q] * inv;
            out[(size_t)s * NK + q] = sc;
            if (sc > best) { best = sc; pk = q; }
        }
        out[(size_t)NS * NK + s]      = (float)pk;    // pred
        out[(size_t)NS * NK + NS + s] = (float)gidx;  // clusters
    }
}

extern "C" void kernel_launch(void* const* d_in, const int* in_sizes, int n_in,
                              void* d_out, int out_size, void* d_ws, size_t ws_size,
                              hipStream_t stream)
{
    const float* data = (const float*)d_in[0];
    const float* n    = (const float*)d_in[2];
    const float* mu   = (const float*)d_in[3];
    const float* S    = (const float*)d_in[4];
    const int*   clab = (const int*)d_in[5];

    char* w = (char*)d_ws;
    unsigned short* Qh  = (unsigned short*)(w);                 // 17,825,792 B
    unsigned short* Ql  = (unsigned short*)(w + 17825792);      // 17,825,792 B
    unsigned short* Bph = (unsigned short*)(w + 35651584);      //  2,228,224 B
    unsigned short* Bpl = (unsigned short*)(w + 37879808);      //  2,228,224 B
    float* d2   = (float*)(w + 40108032);                       //  8,388,608 B
    float* labf = (float*)(w + 48496640);                       //      2,048 B

    hipLaunchKernelGGL(prep_kernel,  dim3(NC + QB), dim3(256), 0, stream,
                       data, S, n, mu, clab, Qh, Ql, Bph, Bpl, labf);
    hipLaunchKernelGGL(gemm_kernel,  dim3(NS / 64, NC / 32), dim3(256), 0, stream,
                       Qh, Ql, Bph, Bpl, d2);
    hipLaunchKernelGGL(score_kernel, dim3(NS / 4), dim3(256), 0, stream,
                       d2, labf, (float*)d_out);
}

// Round 16
// 142.067 us; speedup vs baseline: 1.0601x; 1.0130x over previous
//
#include <hip/hip_runtime.h>
#include <hip/hip_bf16.h>
#include <math.h>

#define NS 4096      // samples
#define NC 512       // clusters
#define ND 64        // feature dim
#define NK 10        // classes
#define NPAIR 2080   // upper-triangle pairs (e<=d) of 64x64
#define KP 2176      // 2080 + 64 (linear) + 1 (const) + 31 zero-pad; 68*32
#define BOFF 2080
#define KOFF 2144
#define QB 2048                     // Q-precompute blocks (2 rows each)
#define KT 68                       // full-K chunks (no split)

typedef __attribute__((ext_vector_type(8))) short short8;
typedef __attribute__((ext_vector_type(4))) float floatx4;

__device__ inline unsigned short f2b(float x) {
    __hip_bfloat16 h = __float2bfloat16(x);           // RNE
    return __builtin_bit_cast(unsigned short, h);
}
__device__ inline float b2f(unsigned short u) {
    __hip_bfloat16 h = __builtin_bit_cast(__hip_bfloat16, u);
    return __bfloat162float(h);
}

// true v_readlane_b32 (lane is a compile-time literal at every use site)
__device__ inline float rlane(float v, int k) {
    return __builtin_bit_cast(float, __builtin_amdgcn_readlane(__builtin_bit_cast(int, v), k));
}

// async global->LDS, 16B per lane (m97 lever); dst = wave-uniform base + lane*16
__device__ inline void gl16(const void* g, void* l) {
    __builtin_amdgcn_global_load_lds(
        (const __attribute__((address_space(1))) unsigned int*)g,
        (__attribute__((address_space(3))) unsigned int*)l, 16, 0, 0);
}

// analytic (e,d) decode (bit-exact, HW-verified R6-R15: absmax 0.0 end-to-end)
__device__ inline uchar2 ed_decode(int p) {
    if (p < NPAIR) {
        const float s = sqrtf((float)(16641 - 8 * p));
        int e = (int)((129.0f - s) * 0.5f);
        int off = e * 64 - (e * (e - 1)) / 2;         // off(e)
        const int offn = off + (64 - e);              // off(e+1)
        if (p >= offn) { off = offn; ++e; }
        else if (p < off) { off -= (65 - e); --e; }
        return make_uchar2((unsigned char)e, (unsigned char)(e + (p - off)));
    } else if (p < KOFF) return make_uchar2((unsigned char)(p - BOFF), 64);
    else if (p == KOFF)  return make_uchar2(64, 64);
    return make_uchar2(65, 65);                       // zero pad
}

// ---------------- prep: 2 roles (R15 body, unchanged) -----------------------
//  role A (blk <  NC):   Sigma^-1 (4-wave coop GJ) + beta pack
//  role C (blk >= NC):   Q precompute, quad-walked
__global__ __launch_bounds__(256, 4) void prep_kernel(
    const float* __restrict__ data, const float* __restrict__ S,
    const float* __restrict__ n, const float* __restrict__ mu,
    const int* __restrict__ clab,
    unsigned short* __restrict__ Qh, unsigned short* __restrict__ Ql,
    unsigned short* __restrict__ Bph, unsigned short* __restrict__ Bpl,
    float* __restrict__ labf)
{
    __shared__ float AcolS[ND * (ND + 1)];            // Sinv mirror [64][65]
    __shared__ float cbuf[ND];                        // bvec staging
    __shared__ float rowbuf[2][ND];                   // GJ pivot-row broadcast
    __shared__ float kksS[1];
    __shared__ float zq[2][66];                       // Q-role rows + sentinels

    if (blockIdx.x >= NC) {                           // ---- role C: Q build --
        const int qb = blockIdx.x - NC;               // 0..QB-1
        const int half = threadIdx.x >> 7;            // 2 rows per block
        const int i = threadIdx.x & 127;              // 2 waves per row
        const int row = qb * 2 + half;
        if (i < 64) zq[half][i] = data[(size_t)row * ND + i];
        else if (i == 64) { zq[half][64] = 1.0f; zq[half][65] = 0.0f; }
        __syncthreads();
        const float* __restrict__ zr = zq[half];
        unsigned short* __restrict__ qh = Qh + (size_t)row * KP;
        unsigned short* __restrict__ ql = Ql + (size_t)row * KP;
        #pragma unroll
        for (int t = 0; t < 4; ++t) {
            const int p0 = t * 512 + i * 4;
            uchar2 ed = ed_decode(p0);
            unsigned short h4[4], l4[4];
            #pragma unroll
            for (int r = 0; r < 4; ++r) {
                const float v = zr[ed.x] * zr[ed.y];
                h4[r] = f2b(v);
                l4[r] = f2b(v - b2f(h4[r]));
                ed = (ed.y < 63) ? make_uchar2(ed.x, (unsigned char)(ed.y + 1))
                                 : make_uchar2((unsigned char)(ed.x + 1),
                                               (unsigned char)(ed.x + 1));
            }
            *(short4*)&qh[p0] = make_short4((short)h4[0], (short)h4[1],
                                            (short)h4[2], (short)h4[3]);
            *(short4*)&ql[p0] = make_short4((short)l4[0], (short)l4[1],
                                            (short)l4[2], (short)l4[3]);
        }
        {                                             // tail: p = 2048 + i
            const int p = 2048 + i;
            const uchar2 ed = ed_decode(p);
            const float v = zr[ed.x] * zr[ed.y];
            const unsigned short h = f2b(v);
            const unsigned short l = f2b(v - b2f(h));
            qh[p] = h;
            ql[p] = l;
        }
        return;
    }

    // ---- role A: 4-wave cooperative Gauss-Jordan ----
    const int c = blockIdx.x;
    const int tid = threadIdx.x;
    const int j = tid & 63;                           // column owned by lane
    const int w = tid >> 6;                           // wave -> rows 16w..16w+15
    const int rbase = w * 16;

    const float inv_nc = 1.0f / n[c];
    const float* __restrict__ Sc = S + (size_t)c * ND * ND + j;

    float4 B0, B1, B2, B3;
    // (1) pure loads -- 16 independent, all issued before any VALU below
#define LOADT(u) \
    const float t##u##0 = Sc[(rbase + 4*(u) + 0) * ND]; \
    const float t##u##1 = Sc[(rbase + 4*(u) + 1) * ND]; \
    const float t##u##2 = Sc[(rbase + 4*(u) + 2) * ND]; \
    const float t##u##3 = Sc[(rbase + 4*(u) + 3) * ND];
    LOADT(0) LOADT(1) LOADT(2) LOADT(3)
#undef LOADT
    __builtin_amdgcn_sched_barrier(0);                // loads stay batched
    // (2) scale + epsilon (same per-element op order as before)
#define SCALE(u) { \
    const float x0 = t##u##0 * inv_nc; \
    const float x1 = t##u##1 * inv_nc; \
    const float x2 = t##u##2 * inv_nc; \
    const float x3 = t##u##3 * inv_nc; \
    B##u.x = (rbase + 4*(u) + 0 == j) ? x0 + 1e-6f : x0; \
    B##u.y = (rbase + 4*(u) + 1 == j) ? x1 + 1e-6f : x1; \
    B##u.z = (rbase + 4*(u) + 2 == j) ? x2 + 1e-6f : x2; \
    B##u.w = (rbase + 4*(u) + 3 == j) ? x3 + 1e-6f : x3; }
    SCALE(0) SCALE(1) SCALE(2) SCALE(3)
#undef SCALE

#define UPD4(u, K) {                                                  \
    const float c0 = rlane(B##u.x, K);                                \
    const float c1 = rlane(B##u.y, K);                                \
    const float c2 = rlane(B##u.z, K);                                \
    const float c3 = rlane(B##u.w, K);                                \
    B##u.x = (om && (4*(u)+0 == ((K)&15))) ? rowk : B##u.x * am - c0 * rowk; \
    B##u.y = (om && (4*(u)+1 == ((K)&15))) ? rowk : B##u.y * am - c1 * rowk; \
    B##u.z = (om && (4*(u)+2 == ((K)&15))) ? rowk : B##u.z * am - c2 * rowk; \
    B##u.w = (om && (4*(u)+3 == ((K)&15))) ? rowk : B##u.w * am - c3 * rowk; \
}
#define STEPC(TL, C, K) {                                             \
    if (w == ((K) >> 4)) {                                            \
        const float rp = B##TL.C;         /* M[k][j]: own register */ \
        const float pv = rlane(rp, K);    /* pivot M[k][k] */         \
        const float ip = 1.0f / pv;                                   \
        rowbuf[(K) & 1][j] = (j == (K)) ? ip : rp * ip;               \
    }                                                                 \
    __syncthreads();                                                  \
    const float rowk = rowbuf[(K) & 1][j];                            \
    const float am = (j == (K)) ? 0.0f : 1.0f;                        \
    const bool om = (w == ((K) >> 4));                                \
    UPD4(0, K) UPD4(1, K) UPD4(2, K) UPD4(3, K)                       \
}
#define STEP4(T, TL) STEPC(TL, x, 4*(T)+0) STEPC(TL, y, 4*(T)+1) \
                     STEPC(TL, z, 4*(T)+2) STEPC(TL, w, 4*(T)+3)
#define FOR16P(M) M(0,0) M(1,1) M(2,2) M(3,3) M(4,0) M(5,1) M(6,2) M(7,3) \
                  M(8,0) M(9,1) M(10,2) M(11,3) M(12,0) M(13,1) M(14,2) M(15,3)
    FOR16P(STEP4)
#undef FOR16P
#undef STEP4
#undef STEPC
#undef UPD4

    // mirror Sinv into LDS for the pack gather (all 4 waves, disjoint rows)
#define MIR(u) *(float4*)&AcolS[j * (ND + 1) + rbase + 4*(u)] = B##u;
    MIR(0) MIR(1) MIR(2) MIR(3)
#undef MIR
    __syncthreads();                                  // AcolS complete

    if (w == 0) {                                     // y = Sinv*mu, kk, labels
        const float* __restrict__ muc = mu + (size_t)c * ND;
        float y = 0.f;
        #pragma unroll
        for (int t = 0; t < 16; ++t) {
            const float4 v = *(const float4*)&AcolS[j * (ND + 1) + 4 * t];
            y += v.x * muc[4*t]     + v.y * muc[4*t + 1]
               + v.z * muc[4*t + 2] + v.w * muc[4*t + 3];
        }
        cbuf[j] = -2.0f * y;                          // bvec values
        float kk = muc[j] * y;
        #pragma unroll
        for (int off = 32; off > 0; off >>= 1) kk += __shfl_down(kk, off);
        if (j == 0) {
            kksS[0] = kk;
            int lab = 0;
            for (int q = 0; q < NK; ++q) if (clab[c * NK + q] != 0) lab = q;
            labf[c] = (float)lab;
        }
    }
    __syncthreads();
    const float kks = kksS[0];

    unsigned short* __restrict__ ph = Bph + (size_t)c * KP;
    unsigned short* __restrict__ pl = Bpl + (size_t)c * KP;
    #pragma unroll
    for (int i = 0; i < 9; ++i) {                     // 34 iters split 4 ways
        const int t = w + 4 * i;
        if (t < KP / 64) {
            const int p = t * 64 + j;
            float val;
            if (p < NPAIR) {
                const uchar2 ed = ed_decode(p);
                val = (ed.x == ed.y) ? AcolS[ed.x * (ND + 1) + ed.x]
                    : (AcolS[ed.y * (ND + 1) + ed.x] + AcolS[ed.x * (ND + 1) + ed.y]);
            } else if (p < KOFF) val = cbuf[p - BOFF];
            else if (p == KOFF)  val = kks;
            else                 val = 0.f;
            const unsigned short h = f2b(val);
            const unsigned short l = f2b(val - b2f(h));
            ph[p] = h;
            pl[p] = l;
        }
    }
}

// ---------------- d2 = Q·Beta^T, 64x64 tile, 2x2 wave quadrants, KSPLIT=1 ---
// R31: R15's WRITE_SIZE=|d2| confirmed the atomic model (-4.5us), exposing
// LDS-read BW as the next pipe: 64x32's Ma=1,Nb=2 frag shape reads 1.0 KB
// LDS per MFMA -> 1.7GB ~ 25us at the 69TB/s ceiling (+6.7M conflict cy).
// Fix: 64x64 tile, each wave owns a 32x32 QUADRANT (Ma=2,Nb=2): 8 frag-pair
// reads per 12 MFMA = 0.67 KB/MFMA -> 1.1GB (~16us); staging 836->557MB.
// Grid (64,8)=512 = 2 blocks/CU (R14 measured occupancy-doubling null, so
// 25% occ accepted). Same skeleton: 2-buffer ring, counted vmcnt(4), same
// swizzle algebra (quadrant bases multiple of 16 keep the seg-XOR invariant),
// same per-(m,n) chunk order + 3-MFMA hi/lo sequence -> d2 bit-identical.
__global__ __launch_bounds__(256, 2) void gemm_kernel(
    const unsigned short* __restrict__ Qh, const unsigned short* __restrict__ Ql,
    const unsigned short* __restrict__ Bph, const unsigned short* __restrict__ Bpl,
    float* __restrict__ d2)
{
    __shared__ unsigned short AhS[2][64 * 32], AlS[2][64 * 32];   // 16KB
    __shared__ unsigned short BhS[2][64 * 32], BlS[2][64 * 32];   // 16KB

    const int tid  = threadIdx.x;
    const int lane = tid & 63, w = tid >> 6;
    const int quad = lane >> 4, rlo = lane & 15;
    const int wr = (w >> 1) * 32, wc = (w & 1) * 32;  // wave quadrant base

    const int m0 = blockIdx.x * 64;               // sample tile
    const int n0 = blockIdx.y * 64;               // cluster tile

    // staging: thread -> row tid>>2, seg tid&3; source seg pre-swizzled so
    // LDS[row][slot] = global seg slot^((row>>2)&3); dst linear tid*16B.
    const int srow = tid >> 2;
    const int sswz = (tid & 3) ^ ((srow >> 2) & 3);
    const unsigned short* aGh = Qh + (size_t)(m0 + srow) * KP + sswz * 8;
    const unsigned short* aGl = Ql + (size_t)(m0 + srow) * KP + sswz * 8;
    const unsigned short* bGh = Bph + (size_t)(n0 + srow) * KP + sswz * 8;
    const unsigned short* bGl = Bpl + (size_t)(n0 + srow) * KP + sswz * 8;
    const int swz8 = (quad ^ ((rlo >> 2) & 3)) * 8;   // read-side slot

    floatx4 acc[2][2] = {};

#define STAGE(b, t) {                                                 \
        const int _ko = (t) * 32;                                     \
        gl16(aGh + _ko, &AhS[b][tid * 8]);                            \
        gl16(aGl + _ko, &AlS[b][tid * 8]);                            \
        gl16(bGh + _ko, &BhS[b][tid * 8]);                            \
        gl16(bGl + _ko, &BlS[b][tid * 8]);                            \
    }

    // prologue: tiles 0 and 1 in flight (4 loads each); wait for tile 0
    STAGE(0, 0)
    STAGE(1, 1)
    asm volatile("s_waitcnt vmcnt(4)" ::: "memory");
    __builtin_amdgcn_s_barrier();
    __builtin_amdgcn_sched_barrier(0);

    for (int kt = 0; kt < KT; ++kt) {
        const int cur = kt & 1;

        // compiler-visible ds_reads: scheduler interleaves with MFMAs below
        short8 ah[2], al[2], bh[2], bl[2];
        #pragma unroll
        for (int i = 0; i < 2; ++i) {
            ah[i] = *(const short8*)&AhS[cur][(wr + i * 16 + rlo) * 32 + swz8];
            al[i] = *(const short8*)&AlS[cur][(wr + i * 16 + rlo) * 32 + swz8];
        }
        #pragma unroll
        for (int j2 = 0; j2 < 2; ++j2) {
            bh[j2] = *(const short8*)&BhS[cur][(wc + j2 * 16 + rlo) * 32 + swz8];
            bl[j2] = *(const short8*)&BlS[cur][(wc + j2 * 16 + rlo) * 32 + swz8];
        }

        __builtin_amdgcn_s_setprio(1);
        #pragma unroll
        for (int i = 0; i < 2; ++i)
            #pragma unroll
            for (int j2 = 0; j2 < 2; ++j2) {
                acc[i][j2] = __builtin_amdgcn_mfma_f32_16x16x32_bf16(al[i], bh[j2], acc[i][j2], 0, 0, 0);
                acc[i][j2] = __builtin_amdgcn_mfma_f32_16x16x32_bf16(ah[i], bl[j2], acc[i][j2], 0, 0, 0);
                acc[i][j2] = __builtin_amdgcn_mfma_f32_16x16x32_bf16(ah[i], bh[j2], acc[i][j2], 0, 0, 0);
            }
        __builtin_amdgcn_s_setprio(0);

        asm volatile("s_waitcnt lgkmcnt(0)" ::: "memory");
        __builtin_amdgcn_s_barrier();                 // all waves done w/ cur

        if (kt < KT - 2) STAGE(cur, kt + 2)           // overwrite now safe

        if (kt < KT - 2) {
            asm volatile("s_waitcnt vmcnt(4)" ::: "memory");   // kt+1 landed
        } else {
            asm volatile("s_waitcnt vmcnt(0)" ::: "memory");   // tail drain
        }
        __builtin_amdgcn_s_barrier();                 // buf[cur^1] published
        __builtin_amdgcn_sched_barrier(0);            // next reads stay below
    }
#undef STAGE

    // C layout (verified m89): col = lane&15, row = (lane>>4)*4 + reg
    // plain stores -- sole writer of each element (no split-K)
    #pragma unroll
    for (int i = 0; i < 2; ++i)
        #pragma unroll
        for (int j2 = 0; j2 < 2; ++j2) {
            const int m = m0 + wr + i * 16 + quad * 4;
            const int nn = n0 + wc + j2 * 16 + rlo;
            #pragma unroll
            for (int r = 0; r < 4; ++r)
                d2[(size_t)(m + r) * NC + nn] = acc[i][j2][r];
        }
}

// ---------------- scores / argmaxes: 4 waves/block, one sample per wave -----
__global__ __launch_bounds__(256) void score_kernel(
    const float* __restrict__ d2, const float* __restrict__ labf,
    float* __restrict__ out)
{
    const int s = blockIdx.x * 4 + (threadIdx.x >> 6);
    const int l = threadIdx.x & 63;

    float numer[NK];
    #pragma unroll
    for (int q = 0; q < NK; ++q) numer[q] = 0.f;
    float denom = 0.f, gmax = -1.f;
    int gidx = 0;

    #pragma unroll
    for (int i = 0; i < NC / 256; ++i) {         // float4 per lane, index-ascending
        const int c0 = i * 256 + l * 4;
        const float4 v = *(const float4*)&d2[(size_t)s * NC + c0];
        #pragma unroll
        for (int r = 0; r < 4; ++r) {
            const int c = c0 + r;
            const float G = __expf(-0.5f * ((const float*)&v)[r]);
            denom += G;
            const int lab = (int)labf[c];
            #pragma unroll
            for (int q = 0; q < NK; ++q) numer[q] += (q == lab) ? G : 0.f;
            if (G > gmax) { gmax = G; gidx = c; }   // strict > keeps first index
        }
    }

    #pragma unroll
    for (int off = 32; off > 0; off >>= 1) {
        const float og = __shfl_down(gmax, off);
        const int   oi = __shfl_down(gidx, off);
        if (og > gmax || (og == gmax && oi < gidx)) { gmax = og; gidx = oi; }
        denom += __shfl_down(denom, off);
        #pragma unroll
        for (int q = 0; q < NK; ++q) numer[q] += __shfl_down(numer[q], off);
    }

    if (l == 0) {
        const float inv = 1.0f / (denom + 1e-12f);
        float best = -1.f; int pk = 0;
        #pragma unroll
        for (int q = 0; q < NK; ++q) {
            const float sc = numer[q] * inv;
            out[(size_t)s * NK + q] = sc;
            if (sc > best) { best = sc; pk = q; }
        }
        out[(size_t)NS * NK + s]      = (float)pk;    // pred
        out[(size_t)NS * NK + NS + s] = (float)gidx;  // clusters
    }
}

extern "C" void kernel_launch(void* const* d_in, const int* in_sizes, int n_in,
                              void* d_out, int out_size, void* d_ws, size_t ws_size,
                              hipStream_t stream)
{
    const float* data = (const float*)d_in[0];
    const float* n    = (const float*)d_in[2];
    const float* mu   = (const float*)d_in[3];
    const float* S    = (const float*)d_in[4];
    const int*   clab = (const int*)d_in[5];

    char* w = (char*)d_ws;
    unsigned short* Qh  = (unsigned short*)(w);                 // 17,825,792 B
    unsigned short* Ql  = (unsigned short*)(w + 17825792);      // 17,825,792 B
    unsigned short* Bph = (unsigned short*)(w + 35651584);      //  2,228,224 B
    unsigned short* Bpl = (unsigned short*)(w + 37879808);      //  2,228,224 B
    float* d2   = (float*)(w + 40108032);                       //  8,388,608 B
    float* labf = (float*)(w + 48496640);                       //      2,048 B

    hipLaunchKernelGGL(prep_kernel,  dim3(NC + QB), dim3(256), 0, stream,
                       data, S, n, mu, clab, Qh, Ql, Bph, Bpl, labf);
    hipLaunchKernelGGL(gemm_kernel,  dim3(NS / 64, NC / 64), dim3(256), 0, stream,
                       Qh, Ql, Bph, Bpl, d2);
    hipLaunchKernelGGL(score_kernel, dim3(NS / 4), dim3(256), 0, stream,
                       d2, labf, (float*)d_out);
}